// Round 1
// baseline (181.359 us; speedup 1.0000x reference)
//
#include <hip/hip_runtime.h>

// Problem constants (from reference): B,R,P,C,H,W = 4,4096,64,32,256,256
constexpr int TB = 4, TR = 4096, TP = 64, TC = 32, TH = 256, TW = 256;
constexpr long long HW = (long long)TH * TW;                    // 65536
constexpr long long NPTS = (long long)TB * TR * TP;             // 1,048,576
constexpr long long FEATS_ELEMS = NPTS * TC;                    // 33,554,432
constexpr long long TRANS_ELEMS = (long long)TB * 3 * TC * HW;  // 25,165,824

// ---------------------------------------------------------------------------
// Transpose features [B,3,C,H,W] -> [B,3,H,W,C] so one bilinear tap reads a
// contiguous 128B run of 32 channels.
// ---------------------------------------------------------------------------
__global__ __launch_bounds__(256) void transpose_feats(
    const float* __restrict__ in, float* __restrict__ out) {
  __shared__ float tile[32][33];  // [c][x], padded to kill bank conflicts
  const int x0 = blockIdx.x * 32;       // W chunk
  const int y  = blockIdx.y;            // H
  const int pk = blockIdx.z;            // B*3 plane index
  const float* pin  = in  + (long long)pk * TC * HW;
  float*       pout = out + (long long)pk * HW * TC;
  const int tx = threadIdx.x, ty = threadIdx.y;
  // read: rows are channels (stride HW), coalesced in x
#pragma unroll
  for (int i = 0; i < 4; ++i) {
    int c = ty + i * 8;
    tile[c][tx] = pin[(long long)c * HW + (long long)y * TW + x0 + tx];
  }
  __syncthreads();
  // write: out[(y*W + x)*C + c], coalesced in c (=tx)
#pragma unroll
  for (int i = 0; i < 4; ++i) {
    int x = ty + i * 8;
    pout[((long long)y * TW + x0 + x) * TC + tx] = tile[tx][x];
  }
}

// ---------------------------------------------------------------------------
// Bilinear tap accumulate: plane layout [H,W,C], 4 channels per thread.
// grid_sample bilinear, align_corners=False, padding_mode=zeros.
// ---------------------------------------------------------------------------
__device__ __forceinline__ void bilin_acc4(const float* __restrict__ plane,
                                           float x, float y, int c4,
                                           float acc[4]) {
  // fx = (x+1)*W/2 - 0.5
  float fx = fmaf(x, (float)TW * 0.5f, (float)TW * 0.5f - 0.5f);
  float fy = fmaf(y, (float)TH * 0.5f, (float)TH * 0.5f - 0.5f);
  float x0f = floorf(fx), y0f = floorf(fy);
  float wx = fx - x0f, wy = fy - y0f;
  int x0 = (int)x0f, y0 = (int)y0f;
  int x1 = x0 + 1, y1 = y0 + 1;
  float vx0 = (x0 >= 0 && x0 < TW) ? 1.f : 0.f;
  float vx1 = (x1 >= 0 && x1 < TW) ? 1.f : 0.f;
  float vy0 = (y0 >= 0 && y0 < TH) ? 1.f : 0.f;
  float vy1 = (y1 >= 0 && y1 < TH) ? 1.f : 0.f;
  int cx0 = min(max(x0, 0), TW - 1), cx1 = min(max(x1, 0), TW - 1);
  int cy0 = min(max(y0, 0), TH - 1), cy1 = min(max(y1, 0), TH - 1);
  float w00 = (1.f - wx) * (1.f - wy) * vx0 * vy0;
  float w10 = wx * (1.f - wy) * vx1 * vy0;
  float w01 = (1.f - wx) * wy * vx0 * vy1;
  float w11 = wx * wy * vx1 * vy1;
  const float4 v00 = *(const float4*)(plane + ((long long)cy0 * TW + cx0) * TC + c4);
  const float4 v10 = *(const float4*)(plane + ((long long)cy0 * TW + cx1) * TC + c4);
  const float4 v01 = *(const float4*)(plane + ((long long)cy1 * TW + cx0) * TC + c4);
  const float4 v11 = *(const float4*)(plane + ((long long)cy1 * TW + cx1) * TC + c4);
  acc[0] += w00 * v00.x + w10 * v10.x + w01 * v01.x + w11 * v11.x;
  acc[1] += w00 * v00.y + w10 * v10.y + w01 * v01.y + w11 * v11.y;
  acc[2] += w00 * v00.z + w10 * v10.z + w01 * v01.z + w11 * v11.z;
  acc[3] += w00 * v00.w + w10 * v10.w + w01 * v01.w + w11 * v11.w;
}

// Fast path: thread = (point, c4). 8 threads/point, float4 channels.
__global__ __launch_bounds__(256) void sample_fast(
    const float* __restrict__ origins, const float* __restrict__ directions,
    const float* __restrict__ lengths, const float* __restrict__ w2l,
    const float* __restrict__ T, float* __restrict__ out) {
  long long idx = (long long)blockIdx.x * 256 + threadIdx.x;
  long long point = idx >> 3;
  int c4 = ((int)idx & 7) * 4;
  int b = (int)(point / ((long long)TR * TP));
  int rp = (int)(point - (long long)b * TR * TP);
  int r = rp / TP;
  int p = rp - r * TP;
  const float* M = w2l + b * 16;
  long long br = (long long)b * TR + r;
  float ox = origins[br * 3 + 0], oy = origins[br * 3 + 1], oz = origins[br * 3 + 2];
  float dx = directions[br * 3 + 0], dy = directions[br * 3 + 1], dz = directions[br * 3 + 2];
  float t = lengths[br * TP + p];
  // o_local[j] = sum_i o[i]*M[i][j] + M[3][j]   (row-vector * matrix + 4th row)
  float olx = ox * M[0] + oy * M[4] + oz * M[8]  + M[12];
  float oly = ox * M[1] + oy * M[5] + oz * M[9]  + M[13];
  float olz = ox * M[2] + oy * M[6] + oz * M[10] + M[14];
  float dlx = dx * M[0] + dy * M[4] + dz * M[8];
  float dly = dx * M[1] + dy * M[5] + dz * M[9];
  float dlz = dx * M[2] + dy * M[6] + dz * M[10];
  float px = fmaf(dlx, t, olx);
  float py = fmaf(dly, t, oly);
  float pz = fmaf(dlz, t, olz);
  float acc[4] = {0.f, 0.f, 0.f, 0.f};
  const float* base = T + (long long)b * 3 * HW * TC;
  bilin_acc4(base,              px, py, c4, acc);  // k=0: dims (0,1)
  bilin_acc4(base + HW * TC,    px, pz, c4, acc);  // k=1: dims (0,2)
  bilin_acc4(base + 2 * HW * TC, py, pz, c4, acc); // k=2: dims (1,2)
  float4 o4 = make_float4(acc[0], acc[1], acc[2], acc[3]);
  *(float4*)(out + point * TC + c4) = o4;
  if (c4 == 0) {
    bool m = px >= -1.f && px <= 1.f && py >= -1.f && py <= 1.f &&
             pz >= -1.f && pz <= 1.f;
    out[FEATS_ELEMS + point] = m ? 1.f : 0.f;
  }
}

// ---------------------------------------------------------------------------
// Fallback (ws too small): sample directly from [C,H,W]. thread = (point, c).
// ---------------------------------------------------------------------------
__device__ __forceinline__ float bilin1(const float* __restrict__ plane,
                                        float x, float y) {
  float fx = fmaf(x, (float)TW * 0.5f, (float)TW * 0.5f - 0.5f);
  float fy = fmaf(y, (float)TH * 0.5f, (float)TH * 0.5f - 0.5f);
  float x0f = floorf(fx), y0f = floorf(fy);
  float wx = fx - x0f, wy = fy - y0f;
  int x0 = (int)x0f, y0 = (int)y0f;
  int x1 = x0 + 1, y1 = y0 + 1;
  float vx0 = (x0 >= 0 && x0 < TW) ? 1.f : 0.f;
  float vx1 = (x1 >= 0 && x1 < TW) ? 1.f : 0.f;
  float vy0 = (y0 >= 0 && y0 < TH) ? 1.f : 0.f;
  float vy1 = (y1 >= 0 && y1 < TH) ? 1.f : 0.f;
  int cx0 = min(max(x0, 0), TW - 1), cx1 = min(max(x1, 0), TW - 1);
  int cy0 = min(max(y0, 0), TH - 1), cy1 = min(max(y1, 0), TH - 1);
  float w00 = (1.f - wx) * (1.f - wy) * vx0 * vy0;
  float w10 = wx * (1.f - wy) * vx1 * vy0;
  float w01 = (1.f - wx) * wy * vx0 * vy1;
  float w11 = wx * wy * vx1 * vy1;
  return w00 * plane[(long long)cy0 * TW + cx0] +
         w10 * plane[(long long)cy0 * TW + cx1] +
         w01 * plane[(long long)cy1 * TW + cx0] +
         w11 * plane[(long long)cy1 * TW + cx1];
}

__global__ __launch_bounds__(256) void sample_direct(
    const float* __restrict__ origins, const float* __restrict__ directions,
    const float* __restrict__ lengths, const float* __restrict__ w2l,
    const float* __restrict__ feats, float* __restrict__ out) {
  long long idx = (long long)blockIdx.x * 256 + threadIdx.x;
  long long point = idx >> 5;
  int c = (int)idx & 31;
  int b = (int)(point / ((long long)TR * TP));
  int rp = (int)(point - (long long)b * TR * TP);
  int r = rp / TP;
  int p = rp - r * TP;
  const float* M = w2l + b * 16;
  long long br = (long long)b * TR + r;
  float ox = origins[br * 3 + 0], oy = origins[br * 3 + 1], oz = origins[br * 3 + 2];
  float dx = directions[br * 3 + 0], dy = directions[br * 3 + 1], dz = directions[br * 3 + 2];
  float t = lengths[br * TP + p];
  float olx = ox * M[0] + oy * M[4] + oz * M[8]  + M[12];
  float oly = ox * M[1] + oy * M[5] + oz * M[9]  + M[13];
  float olz = ox * M[2] + oy * M[6] + oz * M[10] + M[14];
  float dlx = dx * M[0] + dy * M[4] + dz * M[8];
  float dly = dx * M[1] + dy * M[5] + dz * M[9];
  float dlz = dx * M[2] + dy * M[6] + dz * M[10];
  float px = fmaf(dlx, t, olx);
  float py = fmaf(dly, t, oly);
  float pz = fmaf(dlz, t, olz);
  const float* base = feats + (long long)b * 3 * TC * HW + (long long)c * HW;
  float v = bilin1(base, px, py);
  v += bilin1(base + (long long)TC * HW, px, pz);
  v += bilin1(base + 2ll * TC * HW, py, pz);
  out[point * TC + c] = v;
  if (c == 0) {
    bool m = px >= -1.f && px <= 1.f && py >= -1.f && py <= 1.f &&
             pz >= -1.f && pz <= 1.f;
    out[FEATS_ELEMS + point] = m ? 1.f : 0.f;
  }
}

extern "C" void kernel_launch(void* const* d_in, const int* in_sizes, int n_in,
                              void* d_out, int out_size, void* d_ws, size_t ws_size,
                              hipStream_t stream) {
  const float* origins    = (const float*)d_in[0];
  const float* directions = (const float*)d_in[1];
  const float* lengths    = (const float*)d_in[2];
  const float* features   = (const float*)d_in[3];
  const float* w2l        = (const float*)d_in[4];
  float* out = (float*)d_out;

  const size_t need = (size_t)TRANS_ELEMS * sizeof(float);
  if (ws_size >= need) {
    float* T = (float*)d_ws;
    dim3 tg(TW / 32, TH, TB * 3), tb(32, 8);
    transpose_feats<<<tg, tb, 0, stream>>>(features, T);
    long long total = NPTS * 8;  // 8 threads per point (float4 channels)
    sample_fast<<<(int)(total / 256), 256, 0, stream>>>(
        origins, directions, lengths, w2l, T, out);
  } else {
    long long total = NPTS * 32;  // 1 thread per (point, channel)
    sample_direct<<<(int)(total / 256), 256, 0, stream>>>(
        origins, directions, lengths, w2l, features, out);
  }
}

// Round 3
// 132.907 us; speedup vs baseline: 1.3646x; 1.3646x over previous
//
#include <hip/hip_runtime.h>
#include <hip/hip_fp16.h>

// Problem constants (from reference): B,R,P,C,H,W = 4,4096,64,32,256,256
constexpr int TB = 4, TR = 4096, TP = 64, TC = 32, TH = 256, TW = 256;
constexpr long long HW = (long long)TH * TW;                    // 65536
constexpr long long NPTS = (long long)TB * TR * TP;             // 1,048,576
constexpr long long FEATS_ELEMS = NPTS * TC;                    // 33,554,432
constexpr long long TRANS_ELEMS = (long long)TB * 3 * TC * HW;  // 25,165,824

typedef float fvec4 __attribute__((ext_vector_type(4)));  // builtin vec for nt-store

// ---------------------------------------------------------------------------
// Transpose+downconvert features [B,3,C,H,W] f32 -> [B,3,H,W,C] fp16 so one
// bilinear tap is a contiguous 64B run of 32 half channels.
// ---------------------------------------------------------------------------
__global__ __launch_bounds__(256) void transpose_feats(
    const float* __restrict__ in, __half* __restrict__ out) {
  __shared__ float tile[32][33];  // [c][x], padded
  const int x0 = blockIdx.x * 32;       // W chunk
  const int y  = blockIdx.y;            // H
  const int pk = blockIdx.z;            // B*3 plane index
  const float* pin  = in  + (long long)pk * TC * HW;
  __half*      pout = out + (long long)pk * HW * TC;
  const int tx = threadIdx.x, ty = threadIdx.y;
  const int t = ty * 32 + tx;
  // read: rows are channels (stride HW), coalesced in x; read-once -> nt
#pragma unroll
  for (int i = 0; i < 4; ++i) {
    int c = ty + i * 8;
    tile[c][tx] = __builtin_nontemporal_load(
        pin + (long long)c * HW + (long long)y * TW + x0 + tx);
  }
  __syncthreads();
  // write: out[(y*W + x)*C + c] as half2 (channel pairs), coalesced
#pragma unroll
  for (int i = 0; i < 2; ++i) {
    int pair = t + i * 256;        // 0..511
    int x  = pair >> 4;            // 0..31
    int c2 = pair & 15;            // channel pair 0..15
    float2 f = make_float2(tile[2 * c2][x], tile[2 * c2 + 1][x]);
    __half2 h = __float22half2_rn(f);
    unsigned int bits;
    __builtin_memcpy(&bits, &h, 4);
    __builtin_nontemporal_store(
        bits, (unsigned int*)(pout + ((long long)y * TW + x0 + x) * TC + 2 * c2));
  }
}

// ---------------------------------------------------------------------------
// Bilinear tap accumulate: plane layout [H,W,C] fp16, 4 channels per thread.
// grid_sample bilinear, align_corners=False, padding_mode=zeros.
// ---------------------------------------------------------------------------
__device__ __forceinline__ void load4h(const __half* __restrict__ p, float f[4]) {
  uint2 r = *(const uint2*)p;  // 4 halves, 8B aligned
  __half2 h0 = *reinterpret_cast<const __half2*>(&r.x);
  __half2 h1 = *reinterpret_cast<const __half2*>(&r.y);
  float2 a = __half22float2(h0), b = __half22float2(h1);
  f[0] = a.x; f[1] = a.y; f[2] = b.x; f[3] = b.y;
}

__device__ __forceinline__ void bilin_acc4(const __half* __restrict__ plane,
                                           float x, float y, int c4,
                                           float acc[4]) {
  float fx = fmaf(x, (float)TW * 0.5f, (float)TW * 0.5f - 0.5f);
  float fy = fmaf(y, (float)TH * 0.5f, (float)TH * 0.5f - 0.5f);
  float x0f = floorf(fx), y0f = floorf(fy);
  float wx = fx - x0f, wy = fy - y0f;
  int x0 = (int)x0f, y0 = (int)y0f;
  int x1 = x0 + 1, y1 = y0 + 1;
  float vx0 = (x0 >= 0 && x0 < TW) ? 1.f : 0.f;
  float vx1 = (x1 >= 0 && x1 < TW) ? 1.f : 0.f;
  float vy0 = (y0 >= 0 && y0 < TH) ? 1.f : 0.f;
  float vy1 = (y1 >= 0 && y1 < TH) ? 1.f : 0.f;
  int cx0 = min(max(x0, 0), TW - 1), cx1 = min(max(x1, 0), TW - 1);
  int cy0 = min(max(y0, 0), TH - 1), cy1 = min(max(y1, 0), TH - 1);
  float w00 = (1.f - wx) * (1.f - wy) * vx0 * vy0;
  float w10 = wx * (1.f - wy) * vx1 * vy0;
  float w01 = (1.f - wx) * wy * vx0 * vy1;
  float w11 = wx * wy * vx1 * vy1;
  float v00[4], v10[4], v01[4], v11[4];
  load4h(plane + ((long long)cy0 * TW + cx0) * TC + c4, v00);
  load4h(plane + ((long long)cy0 * TW + cx1) * TC + c4, v10);
  load4h(plane + ((long long)cy1 * TW + cx0) * TC + c4, v01);
  load4h(plane + ((long long)cy1 * TW + cx1) * TC + c4, v11);
#pragma unroll
  for (int i = 0; i < 4; ++i)
    acc[i] += w00 * v00[i] + w10 * v10[i] + w01 * v01[i] + w11 * v11[i];
}

// Fast path: thread = (point, c4). 8 threads/point, 4 half channels each.
__global__ __launch_bounds__(256) void sample_fast(
    const float* __restrict__ origins, const float* __restrict__ directions,
    const float* __restrict__ lengths, const float* __restrict__ w2l,
    const __half* __restrict__ T, float* __restrict__ out) {
  long long idx = (long long)blockIdx.x * 256 + threadIdx.x;
  long long point = idx >> 3;
  int c4 = ((int)idx & 7) * 4;
  int b = (int)(point / ((long long)TR * TP));
  int rp = (int)(point - (long long)b * TR * TP);
  int r = rp / TP;
  int p = rp - r * TP;
  const float* M = w2l + b * 16;
  long long br = (long long)b * TR + r;
  float ox = origins[br * 3 + 0], oy = origins[br * 3 + 1], oz = origins[br * 3 + 2];
  float dx = directions[br * 3 + 0], dy = directions[br * 3 + 1], dz = directions[br * 3 + 2];
  float t = lengths[br * TP + p];
  float olx = ox * M[0] + oy * M[4] + oz * M[8]  + M[12];
  float oly = ox * M[1] + oy * M[5] + oz * M[9]  + M[13];
  float olz = ox * M[2] + oy * M[6] + oz * M[10] + M[14];
  float dlx = dx * M[0] + dy * M[4] + dz * M[8];
  float dly = dx * M[1] + dy * M[5] + dz * M[9];
  float dlz = dx * M[2] + dy * M[6] + dz * M[10];
  float px = fmaf(dlx, t, olx);
  float py = fmaf(dly, t, oly);
  float pz = fmaf(dlz, t, olz);
  float acc[4] = {0.f, 0.f, 0.f, 0.f};
  const __half* base = T + (long long)b * 3 * HW * TC;
  bilin_acc4(base,               px, py, c4, acc);  // k=0: dims (0,1)
  bilin_acc4(base + HW * TC,     px, pz, c4, acc);  // k=1: dims (0,2)
  bilin_acc4(base + 2 * HW * TC, py, pz, c4, acc);  // k=2: dims (1,2)
  fvec4 o4 = {acc[0], acc[1], acc[2], acc[3]};
  // streaming output: keep it out of L2 so gather lines stay resident
  __builtin_nontemporal_store(o4, (fvec4*)(out + point * TC + c4));
  if (c4 == 0) {
    bool m = px >= -1.f && px <= 1.f && py >= -1.f && py <= 1.f &&
             pz >= -1.f && pz <= 1.f;
    __builtin_nontemporal_store(m ? 1.f : 0.f, out + FEATS_ELEMS + point);
  }
}

// ---------------------------------------------------------------------------
// Fallback (ws too small): sample directly from [C,H,W] f32. thread=(point,c).
// ---------------------------------------------------------------------------
__device__ __forceinline__ float bilin1(const float* __restrict__ plane,
                                        float x, float y) {
  float fx = fmaf(x, (float)TW * 0.5f, (float)TW * 0.5f - 0.5f);
  float fy = fmaf(y, (float)TH * 0.5f, (float)TH * 0.5f - 0.5f);
  float x0f = floorf(fx), y0f = floorf(fy);
  float wx = fx - x0f, wy = fy - y0f;
  int x0 = (int)x0f, y0 = (int)y0f;
  int x1 = x0 + 1, y1 = y0 + 1;
  float vx0 = (x0 >= 0 && x0 < TW) ? 1.f : 0.f;
  float vx1 = (x1 >= 0 && x1 < TW) ? 1.f : 0.f;
  float vy0 = (y0 >= 0 && y0 < TH) ? 1.f : 0.f;
  float vy1 = (y1 >= 0 && y1 < TH) ? 1.f : 0.f;
  int cx0 = min(max(x0, 0), TW - 1), cx1 = min(max(x1, 0), TW - 1);
  int cy0 = min(max(y0, 0), TH - 1), cy1 = min(max(y1, 0), TH - 1);
  float w00 = (1.f - wx) * (1.f - wy) * vx0 * vy0;
  float w10 = wx * (1.f - wy) * vx1 * vy0;
  float w01 = (1.f - wx) * wy * vx0 * vy1;
  float w11 = wx * wy * vx1 * vy1;
  return w00 * plane[(long long)cy0 * TW + cx0] +
         w10 * plane[(long long)cy0 * TW + cx1] +
         w01 * plane[(long long)cy1 * TW + cx0] +
         w11 * plane[(long long)cy1 * TW + cx1];
}

__global__ __launch_bounds__(256) void sample_direct(
    const float* __restrict__ origins, const float* __restrict__ directions,
    const float* __restrict__ lengths, const float* __restrict__ w2l,
    const float* __restrict__ feats, float* __restrict__ out) {
  long long idx = (long long)blockIdx.x * 256 + threadIdx.x;
  long long point = idx >> 5;
  int c = (int)idx & 31;
  int b = (int)(point / ((long long)TR * TP));
  int rp = (int)(point - (long long)b * TR * TP);
  int r = rp / TP;
  int p = rp - r * TP;
  const float* M = w2l + b * 16;
  long long br = (long long)b * TR + r;
  float ox = origins[br * 3 + 0], oy = origins[br * 3 + 1], oz = origins[br * 3 + 2];
  float dx = directions[br * 3 + 0], dy = directions[br * 3 + 1], dz = directions[br * 3 + 2];
  float t = lengths[br * TP + p];
  float olx = ox * M[0] + oy * M[4] + oz * M[8]  + M[12];
  float oly = ox * M[1] + oy * M[5] + oz * M[9]  + M[13];
  float olz = ox * M[2] + oy * M[6] + oz * M[10] + M[14];
  float dlx = dx * M[0] + dy * M[4] + dz * M[8];
  float dly = dx * M[1] + dy * M[5] + dz * M[9];
  float dlz = dx * M[2] + dy * M[6] + dz * M[10];
  float px = fmaf(dlx, t, olx);
  float py = fmaf(dly, t, oly);
  float pz = fmaf(dlz, t, olz);
  const float* base = feats + (long long)b * 3 * TC * HW + (long long)c * HW;
  float v = bilin1(base, px, py);
  v += bilin1(base + (long long)TC * HW, px, pz);
  v += bilin1(base + 2ll * TC * HW, py, pz);
  out[point * TC + c] = v;
  if (c == 0) {
    bool m = px >= -1.f && px <= 1.f && py >= -1.f && py <= 1.f &&
             pz >= -1.f && pz <= 1.f;
    out[FEATS_ELEMS + point] = m ? 1.f : 0.f;
  }
}

extern "C" void kernel_launch(void* const* d_in, const int* in_sizes, int n_in,
                              void* d_out, int out_size, void* d_ws, size_t ws_size,
                              hipStream_t stream) {
  const float* origins    = (const float*)d_in[0];
  const float* directions = (const float*)d_in[1];
  const float* lengths    = (const float*)d_in[2];
  const float* features   = (const float*)d_in[3];
  const float* w2l        = (const float*)d_in[4];
  float* out = (float*)d_out;

  const size_t need = (size_t)TRANS_ELEMS * sizeof(__half);
  if (ws_size >= need) {
    __half* T = (__half*)d_ws;
    dim3 tg(TW / 32, TH, TB * 3), tb(32, 8);
    transpose_feats<<<tg, tb, 0, stream>>>(features, T);
    long long total = NPTS * 8;  // 8 threads per point (4 half channels each)
    sample_fast<<<(int)(total / 256), 256, 0, stream>>>(
        origins, directions, lengths, w2l, T, out);
  } else {
    long long total = NPTS * 32;  // 1 thread per (point, channel)
    sample_direct<<<(int)(total / 256), 256, 0, stream>>>(
        origins, directions, lengths, w2l, features, out);
  }
}

// Round 4
// 131.148 us; speedup vs baseline: 1.3828x; 1.0134x over previous
//
#include <hip/hip_runtime.h>
#include <hip/hip_fp16.h>

// Problem constants (from reference): B,R,P,C,H,W = 4,4096,64,32,256,256
constexpr int TB = 4, TR = 4096, TP = 64, TC = 32, TH = 256, TW = 256;
constexpr long long HW = (long long)TH * TW;                    // 65536
constexpr long long NPTS = (long long)TB * TR * TP;             // 1,048,576
constexpr long long FEATS_ELEMS = NPTS * TC;                    // 33,554,432
constexpr long long TRANS_ELEMS = (long long)TB * 3 * TC * HW;  // 25,165,824
constexpr unsigned PLANE_ELEMS = (unsigned)(HW * TC);           // 2,097,152 halves

typedef float fvec4 __attribute__((ext_vector_type(4)));

// ---------------------------------------------------------------------------
// Transpose+downconvert features [B,3,C,H,W] f32 -> [B,3,H,W,C] fp16.
// ---------------------------------------------------------------------------
__global__ __launch_bounds__(256) void transpose_feats(
    const float* __restrict__ in, __half* __restrict__ out) {
  __shared__ float tile[32][33];
  const int x0 = blockIdx.x * 32;
  const int y  = blockIdx.y;
  const int pk = blockIdx.z;
  const float* pin  = in  + (long long)pk * TC * HW;
  __half*      pout = out + (long long)pk * HW * TC;
  const int tx = threadIdx.x, ty = threadIdx.y;
  const int t = ty * 32 + tx;
#pragma unroll
  for (int i = 0; i < 4; ++i) {
    int c = ty + i * 8;
    tile[c][tx] = __builtin_nontemporal_load(
        pin + (long long)c * HW + (long long)y * TW + x0 + tx);
  }
  __syncthreads();
#pragma unroll
  for (int i = 0; i < 2; ++i) {
    int pair = t + i * 256;
    int x  = pair >> 4;
    int c2 = pair & 15;
    float2 f = make_float2(tile[2 * c2][x], tile[2 * c2 + 1][x]);
    __half2 h = __float22half2_rn(f);
    unsigned int bits;
    __builtin_memcpy(&bits, &h, 4);
    __builtin_nontemporal_store(
        bits, (unsigned int*)(pout + ((long long)y * TW + x0 + x) * TC + 2 * c2));
  }
}

// ---------------------------------------------------------------------------
// Per-ray prologue: world->local transform once per ray (B*R = 16384 rays).
// rays[i] = { ol.xyz, pad, dl.xyz, pad }  (two float4 per ray)
// ---------------------------------------------------------------------------
__global__ __launch_bounds__(256) void rays_kernel(
    const float* __restrict__ o, const float* __restrict__ d,
    const float* __restrict__ w2l, float* __restrict__ rays) {
  int i = blockIdx.x * 256 + threadIdx.x;
  if (i >= TB * TR) return;
  int b = i >> 12;  // TR = 4096
  const float* M = w2l + b * 16;
  float ox = o[i * 3], oy = o[i * 3 + 1], oz = o[i * 3 + 2];
  float dx = d[i * 3], dy = d[i * 3 + 1], dz = d[i * 3 + 2];
  fvec4 ol = {ox * M[0] + oy * M[4] + oz * M[8]  + M[12],
              ox * M[1] + oy * M[5] + oz * M[9]  + M[13],
              ox * M[2] + oy * M[6] + oz * M[10] + M[14], 0.f};
  fvec4 dl = {dx * M[0] + dy * M[4] + dz * M[8],
              dx * M[1] + dy * M[5] + dz * M[9],
              dx * M[2] + dy * M[6] + dz * M[10], 0.f};
  ((fvec4*)rays)[i * 2]     = ol;
  ((fvec4*)rays)[i * 2 + 1] = dl;
}

// ---------------------------------------------------------------------------
// Tap prep: offsets (in half-elements, c4 folded into ebase) + folded weights.
// ---------------------------------------------------------------------------
__device__ __forceinline__ void prep_plane(float x, float y, unsigned ebase,
                                           unsigned* offs, float* w) {
  float fx = fmaf(x, 128.f, 127.5f);
  float fy = fmaf(y, 128.f, 127.5f);
  float x0f = floorf(fx), y0f = floorf(fy);
  float wx = fx - x0f, wy = fy - y0f;
  int x0 = (int)x0f, y0 = (int)y0f;
  int x1 = x0 + 1, y1 = y0 + 1;
  float vx0 = (x0 >= 0 && x0 < TW) ? 1.f : 0.f;
  float vx1 = (x1 >= 0 && x1 < TW) ? 1.f : 0.f;
  float vy0 = (y0 >= 0 && y0 < TH) ? 1.f : 0.f;
  float vy1 = (y1 >= 0 && y1 < TH) ? 1.f : 0.f;
  unsigned cx0 = (unsigned)min(max(x0, 0), TW - 1);
  unsigned cx1 = (unsigned)min(max(x1, 0), TW - 1);
  unsigned cy0 = (unsigned)min(max(y0, 0), TH - 1);
  unsigned cy1 = (unsigned)min(max(y1, 0), TH - 1);
  w[0] = (1.f - wx) * (1.f - wy) * vx0 * vy0;
  w[1] = wx * (1.f - wy) * vx1 * vy0;
  w[2] = (1.f - wx) * wy * vx0 * vy1;
  w[3] = wx * wy * vx1 * vy1;
  unsigned r0 = ebase + (cy0 << 13), r1 = ebase + (cy1 << 13);
  offs[0] = r0 + (cx0 << 5);
  offs[1] = r0 + (cx1 << 5);
  offs[2] = r1 + (cx0 << 5);
  offs[3] = r1 + (cx1 << 5);
}

// ---------------------------------------------------------------------------
// Sampler: block = 32 points (one shared ray), thread = (point, c4).
// All 12 gathers issued up front for ILP; uniform ray data via s_load.
// ---------------------------------------------------------------------------
__global__ __launch_bounds__(256) void sample_fast(
    const float* __restrict__ lengths, const float* __restrict__ rays,
    const __half* __restrict__ T, float* __restrict__ out) {
  const int blk = blockIdx.x;
  const int b  = blk >> 13;            // 8192 blocks per batch
  const int rp = blk & 8191;
  const int r  = rp >> 1;              // 32 points/block, 64 points/ray
  const int p_base = (rp & 1) << 5;
  const int br = (b << 12) + r;        // b*TR + r
  const fvec4 ol = ((const fvec4*)rays)[br * 2];
  const fvec4 dl = ((const fvec4*)rays)[br * 2 + 1];
  const int tid = threadIdx.x;
  const int pl  = tid >> 3;            // point within block: 0..31
  const int c4  = (tid & 7) << 2;      // channel quad
  const int p   = p_base + pl;
  const float t = lengths[(long long)br * TP + p];
  const float px = fmaf(dl.x, t, ol.x);
  const float py = fmaf(dl.y, t, ol.y);
  const float pz = fmaf(dl.z, t, ol.z);

  unsigned offs[12];
  float w[12];
  prep_plane(px, py, (unsigned)c4,                  offs + 0, w + 0);
  prep_plane(px, pz, (unsigned)c4 + PLANE_ELEMS,    offs + 4, w + 4);
  prep_plane(py, pz, (unsigned)c4 + 2 * PLANE_ELEMS, offs + 8, w + 8);

  const __half* Tb = T + (size_t)b * (3 * (size_t)PLANE_ELEMS);
  uint2 v[12];
#pragma unroll
  for (int i = 0; i < 12; ++i)
    v[i] = *(const uint2*)(Tb + offs[i]);

  float acc0 = 0.f, acc1 = 0.f, acc2 = 0.f, acc3 = 0.f;
#pragma unroll
  for (int i = 0; i < 12; ++i) {
    __half2 h0, h1;
    __builtin_memcpy(&h0, &v[i].x, 4);
    __builtin_memcpy(&h1, &v[i].y, 4);
    float2 a = __half22float2(h0);
    float2 c = __half22float2(h1);
    acc0 = fmaf(w[i], a.x, acc0);
    acc1 = fmaf(w[i], a.y, acc1);
    acc2 = fmaf(w[i], c.x, acc2);
    acc3 = fmaf(w[i], c.y, acc3);
  }

  const long long point = (long long)blk * 32 + pl;
  fvec4 o4 = {acc0, acc1, acc2, acc3};
  __builtin_nontemporal_store(o4, (fvec4*)(out + point * TC + c4));
  if (c4 == 0) {
    bool m = px >= -1.f && px <= 1.f && py >= -1.f && py <= 1.f &&
             pz >= -1.f && pz <= 1.f;
    __builtin_nontemporal_store(m ? 1.f : 0.f, out + FEATS_ELEMS + point);
  }
}

// ---------------------------------------------------------------------------
// Fallback (ws too small): sample directly from [C,H,W] f32. thread=(point,c).
// ---------------------------------------------------------------------------
__device__ __forceinline__ float bilin1(const float* __restrict__ plane,
                                        float x, float y) {
  float fx = fmaf(x, 128.f, 127.5f);
  float fy = fmaf(y, 128.f, 127.5f);
  float x0f = floorf(fx), y0f = floorf(fy);
  float wx = fx - x0f, wy = fy - y0f;
  int x0 = (int)x0f, y0 = (int)y0f;
  int x1 = x0 + 1, y1 = y0 + 1;
  float vx0 = (x0 >= 0 && x0 < TW) ? 1.f : 0.f;
  float vx1 = (x1 >= 0 && x1 < TW) ? 1.f : 0.f;
  float vy0 = (y0 >= 0 && y0 < TH) ? 1.f : 0.f;
  float vy1 = (y1 >= 0 && y1 < TH) ? 1.f : 0.f;
  int cx0 = min(max(x0, 0), TW - 1), cx1 = min(max(x1, 0), TW - 1);
  int cy0 = min(max(y0, 0), TH - 1), cy1 = min(max(y1, 0), TH - 1);
  float w00 = (1.f - wx) * (1.f - wy) * vx0 * vy0;
  float w10 = wx * (1.f - wy) * vx1 * vy0;
  float w01 = (1.f - wx) * wy * vx0 * vy1;
  float w11 = wx * wy * vx1 * vy1;
  return w00 * plane[(long long)cy0 * TW + cx0] +
         w10 * plane[(long long)cy0 * TW + cx1] +
         w01 * plane[(long long)cy1 * TW + cx0] +
         w11 * plane[(long long)cy1 * TW + cx1];
}

__global__ __launch_bounds__(256) void sample_direct(
    const float* __restrict__ origins, const float* __restrict__ directions,
    const float* __restrict__ lengths, const float* __restrict__ w2l,
    const float* __restrict__ feats, float* __restrict__ out) {
  long long idx = (long long)blockIdx.x * 256 + threadIdx.x;
  long long point = idx >> 5;
  int c = (int)idx & 31;
  int b = (int)(point / ((long long)TR * TP));
  int rp = (int)(point - (long long)b * TR * TP);
  int r = rp / TP;
  int p = rp - r * TP;
  const float* M = w2l + b * 16;
  long long br = (long long)b * TR + r;
  float ox = origins[br * 3 + 0], oy = origins[br * 3 + 1], oz = origins[br * 3 + 2];
  float dx = directions[br * 3 + 0], dy = directions[br * 3 + 1], dz = directions[br * 3 + 2];
  float t = lengths[br * TP + p];
  float olx = ox * M[0] + oy * M[4] + oz * M[8]  + M[12];
  float oly = ox * M[1] + oy * M[5] + oz * M[9]  + M[13];
  float olz = ox * M[2] + oy * M[6] + oz * M[10] + M[14];
  float dlx = dx * M[0] + dy * M[4] + dz * M[8];
  float dly = dx * M[1] + dy * M[5] + dz * M[9];
  float dlz = dx * M[2] + dy * M[6] + dz * M[10];
  float px = fmaf(dlx, t, olx);
  float py = fmaf(dly, t, oly);
  float pz = fmaf(dlz, t, olz);
  const float* base = feats + (long long)b * 3 * TC * HW + (long long)c * HW;
  float v = bilin1(base, px, py);
  v += bilin1(base + (long long)TC * HW, px, pz);
  v += bilin1(base + 2ll * TC * HW, py, pz);
  out[point * TC + c] = v;
  if (c == 0) {
    bool m = px >= -1.f && px <= 1.f && py >= -1.f && py <= 1.f &&
             pz >= -1.f && pz <= 1.f;
    out[FEATS_ELEMS + point] = m ? 1.f : 0.f;
  }
}

extern "C" void kernel_launch(void* const* d_in, const int* in_sizes, int n_in,
                              void* d_out, int out_size, void* d_ws, size_t ws_size,
                              hipStream_t stream) {
  const float* origins    = (const float*)d_in[0];
  const float* directions = (const float*)d_in[1];
  const float* lengths    = (const float*)d_in[2];
  const float* features   = (const float*)d_in[3];
  const float* w2l        = (const float*)d_in[4];
  float* out = (float*)d_out;

  const size_t table_bytes = (size_t)TRANS_ELEMS * sizeof(__half);   // 50.3 MB
  const size_t rays_bytes  = (size_t)TB * TR * 8 * sizeof(float);    // 512 KB
  if (ws_size >= table_bytes + rays_bytes) {
    __half* T  = (__half*)d_ws;
    float* rays = (float*)((char*)d_ws + table_bytes);
    dim3 tg(TW / 32, TH, TB * 3), tb(32, 8);
    transpose_feats<<<tg, tb, 0, stream>>>(features, T);
    rays_kernel<<<(TB * TR + 255) / 256, 256, 0, stream>>>(
        origins, directions, w2l, rays);
    long long total = NPTS * 8;  // 8 threads per point
    sample_fast<<<(int)(total / 256), 256, 0, stream>>>(lengths, rays, T, out);
  } else {
    long long total = NPTS * 32;
    sample_direct<<<(int)(total / 256), 256, 0, stream>>>(
        origins, directions, lengths, w2l, features, out);
  }
}

// Round 5
// 121.005 us; speedup vs baseline: 1.4988x; 1.0838x over previous
//
#include <hip/hip_runtime.h>
#include <hip/hip_fp16.h>

// Problem constants (from reference): B,R,P,C,H,W = 4,4096,64,32,256,256
constexpr int TB = 4, TR = 4096, TP = 64, TC = 32, TH = 256, TW = 256;
constexpr long long HW = (long long)TH * TW;                    // 65536
constexpr long long NPTS = (long long)TB * TR * TP;             // 1,048,576
constexpr long long FEATS_ELEMS = NPTS * TC;                    // 33,554,432
constexpr long long TRANS_ELEMS = (long long)TB * 3 * TC * HW;  // 25,165,824
constexpr unsigned PLANE_ELEMS = (unsigned)(HW * TC);           // 2,097,152 halves

typedef float fvec4 __attribute__((ext_vector_type(4)));
typedef unsigned uvec4 __attribute__((ext_vector_type(4)));

// ---------------------------------------------------------------------------
// Transpose+downconvert features [B,3,C,H,W] f32 -> [B,3,H,W,C] fp16.
// ---------------------------------------------------------------------------
__global__ __launch_bounds__(256) void transpose_feats(
    const float* __restrict__ in, __half* __restrict__ out) {
  __shared__ float tile[32][33];
  const int x0 = blockIdx.x * 32;
  const int y  = blockIdx.y;
  const int pk = blockIdx.z;
  const float* pin  = in  + (long long)pk * TC * HW;
  __half*      pout = out + (long long)pk * HW * TC;
  const int tx = threadIdx.x, ty = threadIdx.y;
  const int t = ty * 32 + tx;
#pragma unroll
  for (int i = 0; i < 4; ++i) {
    int c = ty + i * 8;
    tile[c][tx] = __builtin_nontemporal_load(
        pin + (long long)c * HW + (long long)y * TW + x0 + tx);
  }
  __syncthreads();
#pragma unroll
  for (int i = 0; i < 2; ++i) {
    int pair = t + i * 256;
    int x  = pair >> 4;
    int c2 = pair & 15;
    float2 f = make_float2(tile[2 * c2][x], tile[2 * c2 + 1][x]);
    __half2 h = __float22half2_rn(f);
    unsigned int bits;
    __builtin_memcpy(&bits, &h, 4);
    __builtin_nontemporal_store(
        bits, (unsigned int*)(pout + ((long long)y * TW + x0 + x) * TC + 2 * c2));
  }
}

// ---------------------------------------------------------------------------
// Per-ray prologue: world->local transform once per ray (B*R = 16384 rays).
// ---------------------------------------------------------------------------
__global__ __launch_bounds__(256) void rays_kernel(
    const float* __restrict__ o, const float* __restrict__ d,
    const float* __restrict__ w2l, float* __restrict__ rays) {
  int i = blockIdx.x * 256 + threadIdx.x;
  if (i >= TB * TR) return;
  int b = i >> 12;  // TR = 4096
  const float* M = w2l + b * 16;
  float ox = o[i * 3], oy = o[i * 3 + 1], oz = o[i * 3 + 2];
  float dx = d[i * 3], dy = d[i * 3 + 1], dz = d[i * 3 + 2];
  fvec4 ol = {ox * M[0] + oy * M[4] + oz * M[8]  + M[12],
              ox * M[1] + oy * M[5] + oz * M[9]  + M[13],
              ox * M[2] + oy * M[6] + oz * M[10] + M[14], 0.f};
  fvec4 dl = {dx * M[0] + dy * M[4] + dz * M[8],
              dx * M[1] + dy * M[5] + dz * M[9],
              dx * M[2] + dy * M[6] + dz * M[10], 0.f};
  ((fvec4*)rays)[i * 2]     = ol;
  ((fvec4*)rays)[i * 2 + 1] = dl;
}

// ---------------------------------------------------------------------------
// Tap prep: offsets (half-element units, channel base folded) + folded weights.
// ---------------------------------------------------------------------------
__device__ __forceinline__ void prep_plane(float x, float y, unsigned ebase,
                                           unsigned* offs, float* w) {
  float fx = fmaf(x, 128.f, 127.5f);
  float fy = fmaf(y, 128.f, 127.5f);
  float x0f = floorf(fx), y0f = floorf(fy);
  float wx = fx - x0f, wy = fy - y0f;
  int x0 = (int)x0f, y0 = (int)y0f;
  int x1 = x0 + 1, y1 = y0 + 1;
  float vx0 = (x0 >= 0 && x0 < TW) ? 1.f : 0.f;
  float vx1 = (x1 >= 0 && x1 < TW) ? 1.f : 0.f;
  float vy0 = (y0 >= 0 && y0 < TH) ? 1.f : 0.f;
  float vy1 = (y1 >= 0 && y1 < TH) ? 1.f : 0.f;
  unsigned cx0 = (unsigned)min(max(x0, 0), TW - 1);
  unsigned cx1 = (unsigned)min(max(x1, 0), TW - 1);
  unsigned cy0 = (unsigned)min(max(y0, 0), TH - 1);
  unsigned cy1 = (unsigned)min(max(y1, 0), TH - 1);
  w[0] = (1.f - wx) * (1.f - wy) * vx0 * vy0;
  w[1] = wx * (1.f - wy) * vx1 * vy0;
  w[2] = (1.f - wx) * wy * vx0 * vy1;
  w[3] = wx * wy * vx1 * vy1;
  unsigned r0 = ebase + (cy0 << 13), r1 = ebase + (cy1 << 13);
  offs[0] = r0 + (cx0 << 5);
  offs[1] = r0 + (cx1 << 5);
  offs[2] = r1 + (cx0 << 5);
  offs[3] = r1 + (cx1 << 5);
}

// ---------------------------------------------------------------------------
// Sampler: block = 1 ray (64 points), thread = (point, c8): 4 lanes/point.
// All 12 tap gathers (dwordx4) issued before any use -> 12-deep MLP.
// ---------------------------------------------------------------------------
__global__ __launch_bounds__(256, 4) void sample_fast(
    const float* __restrict__ lengths, const float* __restrict__ rays,
    const __half* __restrict__ T, float* __restrict__ out) {
  const int br = blockIdx.x;           // one ray per block
  const int b  = br >> 12;             // TR = 4096
  const fvec4 ol = ((const fvec4*)rays)[br * 2];
  const fvec4 dl = ((const fvec4*)rays)[br * 2 + 1];
  const int tid = threadIdx.x;
  const int p   = tid >> 2;            // point 0..63
  const int c8  = (tid & 3) << 3;      // channel octet base: 0,8,16,24
  const float t = lengths[(long long)br * TP + p];
  const float px = fmaf(dl.x, t, ol.x);
  const float py = fmaf(dl.y, t, ol.y);
  const float pz = fmaf(dl.z, t, ol.z);

  unsigned offs[12];
  float w[12];
  prep_plane(px, py, (unsigned)c8,                   offs + 0, w + 0);
  prep_plane(px, pz, (unsigned)c8 + PLANE_ELEMS,     offs + 4, w + 4);
  prep_plane(py, pz, (unsigned)c8 + 2 * PLANE_ELEMS, offs + 8, w + 8);

  const __half* Tb = T + (size_t)b * (3 * (size_t)PLANE_ELEMS);
  uvec4 v[12];
#pragma unroll
  for (int i = 0; i < 12; ++i)
    v[i] = *(const uvec4*)(Tb + offs[i]);
  // Pin: all 12 gathers issued before any unpack/FMA consumes them.
  __builtin_amdgcn_sched_barrier(0);

  float acc[8] = {0.f, 0.f, 0.f, 0.f, 0.f, 0.f, 0.f, 0.f};
#pragma unroll
  for (int i = 0; i < 12; ++i) {
#pragma unroll
    for (int j = 0; j < 4; ++j) {
      unsigned bits = v[i][j];
      __half2 h;
      __builtin_memcpy(&h, &bits, 4);
      float2 f = __half22float2(h);
      acc[2 * j]     = fmaf(w[i], f.x, acc[2 * j]);
      acc[2 * j + 1] = fmaf(w[i], f.y, acc[2 * j + 1]);
    }
  }

  const long long point = (long long)br * 64 + p;
  fvec4 oA = {acc[0], acc[1], acc[2], acc[3]};
  fvec4 oB = {acc[4], acc[5], acc[6], acc[7]};
  float* outp = out + point * TC + c8;
  __builtin_nontemporal_store(oA, (fvec4*)outp);
  __builtin_nontemporal_store(oB, (fvec4*)(outp + 4));
  if (c8 == 0) {
    bool m = px >= -1.f && px <= 1.f && py >= -1.f && py <= 1.f &&
             pz >= -1.f && pz <= 1.f;
    __builtin_nontemporal_store(m ? 1.f : 0.f, out + FEATS_ELEMS + point);
  }
}

// ---------------------------------------------------------------------------
// Fallback (ws too small): sample directly from [C,H,W] f32. thread=(point,c).
// ---------------------------------------------------------------------------
__device__ __forceinline__ float bilin1(const float* __restrict__ plane,
                                        float x, float y) {
  float fx = fmaf(x, 128.f, 127.5f);
  float fy = fmaf(y, 128.f, 127.5f);
  float x0f = floorf(fx), y0f = floorf(fy);
  float wx = fx - x0f, wy = fy - y0f;
  int x0 = (int)x0f, y0 = (int)y0f;
  int x1 = x0 + 1, y1 = y0 + 1;
  float vx0 = (x0 >= 0 && x0 < TW) ? 1.f : 0.f;
  float vx1 = (x1 >= 0 && x1 < TW) ? 1.f : 0.f;
  float vy0 = (y0 >= 0 && y0 < TH) ? 1.f : 0.f;
  float vy1 = (y1 >= 0 && y1 < TH) ? 1.f : 0.f;
  int cx0 = min(max(x0, 0), TW - 1), cx1 = min(max(x1, 0), TW - 1);
  int cy0 = min(max(y0, 0), TH - 1), cy1 = min(max(y1, 0), TH - 1);
  float w00 = (1.f - wx) * (1.f - wy) * vx0 * vy0;
  float w10 = wx * (1.f - wy) * vx1 * vy0;
  float w01 = (1.f - wx) * wy * vx0 * vy1;
  float w11 = wx * wy * vx1 * vy1;
  return w00 * plane[(long long)cy0 * TW + cx0] +
         w10 * plane[(long long)cy0 * TW + cx1] +
         w01 * plane[(long long)cy1 * TW + cx0] +
         w11 * plane[(long long)cy1 * TW + cx1];
}

__global__ __launch_bounds__(256) void sample_direct(
    const float* __restrict__ origins, const float* __restrict__ directions,
    const float* __restrict__ lengths, const float* __restrict__ w2l,
    const float* __restrict__ feats, float* __restrict__ out) {
  long long idx = (long long)blockIdx.x * 256 + threadIdx.x;
  long long point = idx >> 5;
  int c = (int)idx & 31;
  int b = (int)(point / ((long long)TR * TP));
  int rp = (int)(point - (long long)b * TR * TP);
  int r = rp / TP;
  int p = rp - r * TP;
  const float* M = w2l + b * 16;
  long long br = (long long)b * TR + r;
  float ox = origins[br * 3 + 0], oy = origins[br * 3 + 1], oz = origins[br * 3 + 2];
  float dx = directions[br * 3 + 0], dy = directions[br * 3 + 1], dz = directions[br * 3 + 2];
  float t = lengths[br * TP + p];
  float olx = ox * M[0] + oy * M[4] + oz * M[8]  + M[12];
  float oly = ox * M[1] + oy * M[5] + oz * M[9]  + M[13];
  float olz = ox * M[2] + oy * M[6] + oz * M[10] + M[14];
  float dlx = dx * M[0] + dy * M[4] + dz * M[8];
  float dly = dx * M[1] + dy * M[5] + dz * M[9];
  float dlz = dx * M[2] + dy * M[6] + dz * M[10];
  float px = fmaf(dlx, t, olx);
  float py = fmaf(dly, t, oly);
  float pz = fmaf(dlz, t, olz);
  const float* base = feats + (long long)b * 3 * TC * HW + (long long)c * HW;
  float v = bilin1(base, px, py);
  v += bilin1(base + (long long)TC * HW, px, pz);
  v += bilin1(base + 2ll * TC * HW, py, pz);
  out[point * TC + c] = v;
  if (c == 0) {
    bool m = px >= -1.f && px <= 1.f && py >= -1.f && py <= 1.f &&
             pz >= -1.f && pz <= 1.f;
    out[FEATS_ELEMS + point] = m ? 1.f : 0.f;
  }
}

extern "C" void kernel_launch(void* const* d_in, const int* in_sizes, int n_in,
                              void* d_out, int out_size, void* d_ws, size_t ws_size,
                              hipStream_t stream) {
  const float* origins    = (const float*)d_in[0];
  const float* directions = (const float*)d_in[1];
  const float* lengths    = (const float*)d_in[2];
  const float* features   = (const float*)d_in[3];
  const float* w2l        = (const float*)d_in[4];
  float* out = (float*)d_out;

  const size_t table_bytes = (size_t)TRANS_ELEMS * sizeof(__half);   // 50.3 MB
  const size_t rays_bytes  = (size_t)TB * TR * 8 * sizeof(float);    // 512 KB
  if (ws_size >= table_bytes + rays_bytes) {
    __half* T  = (__half*)d_ws;
    float* rays = (float*)((char*)d_ws + table_bytes);
    dim3 tg(TW / 32, TH, TB * 3), tb(32, 8);
    transpose_feats<<<tg, tb, 0, stream>>>(features, T);
    rays_kernel<<<(TB * TR + 255) / 256, 256, 0, stream>>>(
        origins, directions, w2l, rays);
    sample_fast<<<TB * TR, 256, 0, stream>>>(lengths, rays, T, out);
  } else {
    long long total = NPTS * 32;
    sample_direct<<<(int)(total / 256), 256, 0, stream>>>(
        origins, directions, lengths, w2l, features, out);
  }
}